// Round 4
// baseline (140.206 us; speedup 1.0000x reference)
//
#include <hip/hip_runtime.h>
#include <hip/hip_bf16.h>

#define B_ 4
#define S_ 4096
#define D_ 1024
#define H_ 64

typedef __attribute__((ext_vector_type(8))) short bf16x8;
typedef __attribute__((ext_vector_type(4))) float f32x4;

static __device__ __forceinline__ unsigned short f2bf(float f) {
    union { float f; unsigned int i; } v; v.f = f;
    unsigned int r = v.i + 0x7FFFu + ((v.i >> 16) & 1u);  // round-to-nearest-even
    return (unsigned short)(r >> 16);
}

// ---------------------------------------------------------------------------
// Prep: WT[h'][k] = bf16(Wcat[k][h']), h' in [0,192) = {Wq|Wk|Wv}, Q scaled 1/8.
// ---------------------------------------------------------------------------
__global__ __launch_bounds__(256) void prep_w(
    const float* __restrict__ Wq, const float* __restrict__ Wk,
    const float* __restrict__ Wv, unsigned short* __restrict__ WT)
{
    int idx = blockIdx.x * 256 + threadIdx.x;   // 192*1024 total
    int hp = idx >> 10, k = idx & (D_ - 1);
    int y = hp >> 6, h = hp & 63;
    const float* W = (y == 0) ? Wq : (y == 1) ? Wk : Wv;
    float v = W[(size_t)k * H_ + h];
    if (y == 0) v *= 0.125f;
    WT[(size_t)hp * D_ + k] = f2bf(v);
}

// ---------------------------------------------------------------------------
// Projection via bf16 MFMA, LDS-free main loop with a 4-deep register
// prefetch pipeline (24 VMEM ops in flight per wave; no barriers in the
// k-loop, so counted vmcnt waits fully pipeline). grid (256, 3): y -> Q/K/V.
// Each wave: 16 rows x 64 cols. Epilogue via padded per-wave LDS tile;
// V written transposed Vt[b][h][s].
// ---------------------------------------------------------------------------
__global__ __launch_bounds__(256, 3) void proj_mfma(
    const float* __restrict__ x, const unsigned short* __restrict__ WT,
    unsigned short* __restrict__ Qw, unsigned short* __restrict__ Kw,
    unsigned short* __restrict__ Vtw)
{
    __shared__ __align__(16) unsigned short et[4][16][72];  // 72 = 64 + pad

    const int tid = threadIdx.x;
    const int w = tid >> 6, l = tid & 63;
    const int lm = l & 15, lg = l >> 4;
    const int y = blockIdx.y;
    const int row0 = blockIdx.x * 64 + w * 16;

    const unsigned short* Wp = WT + (size_t)y * 64 * D_;
    const float* xp = x + (size_t)(row0 + lm) * D_ + lg * 8;
    const unsigned short* wp = Wp + (size_t)lm * D_ + lg * 8;

    f32x4 acc[4];
    #pragma unroll
    for (int nt = 0; nt < 4; ++nt) acc[nt] = (f32x4){0.f, 0.f, 0.f, 0.f};

    // ---- 4-deep prefetch pipeline (slots d = 0..3, step = 32 k each)
    float4 xa0[4], xa1[4];
    bf16x8 wv[4][4];
    #pragma unroll
    for (int d = 0; d < 4; ++d) {
        xa0[d] = *(const float4*)(xp + d * 32);
        xa1[d] = *(const float4*)(xp + d * 32 + 4);
        #pragma unroll
        for (int nt = 0; nt < 4; ++nt)
            wv[d][nt] = *(const bf16x8*)(wp + (size_t)nt * 16 * D_ + d * 32);
    }

    for (int kc = 0; kc < D_; kc += 128) {
        #pragma unroll
        for (int d = 0; d < 4; ++d) {
            bf16x8 af;
            af[0] = f2bf(xa0[d].x); af[1] = f2bf(xa0[d].y);
            af[2] = f2bf(xa0[d].z); af[3] = f2bf(xa0[d].w);
            af[4] = f2bf(xa1[d].x); af[5] = f2bf(xa1[d].y);
            af[6] = f2bf(xa1[d].z); af[7] = f2bf(xa1[d].w);
            #pragma unroll
            for (int nt = 0; nt < 4; ++nt)
                acc[nt] = __builtin_amdgcn_mfma_f32_16x16x32_bf16(af, wv[d][nt], acc[nt], 0, 0, 0);
            // re-issue slot d for kc+128 (wraps harmlessly on last iter)
            int kn = (kc + 128 + d * 32) & (D_ - 1);
            xa0[d] = *(const float4*)(xp + kn);
            xa1[d] = *(const float4*)(xp + kn + 4);
            #pragma unroll
            for (int nt = 0; nt < 4; ++nt)
                wv[d][nt] = *(const bf16x8*)(wp + (size_t)nt * 16 * D_ + kn);
        }
    }

    // C-frag (row = lg*4+reg, col = nt*16+lm) -> LDS tile [srow][h]
    #pragma unroll
    for (int nt = 0; nt < 4; ++nt)
        #pragma unroll
        for (int reg = 0; reg < 4; ++reg)
            et[w][lg * 4 + reg][nt * 16 + lm] = f2bf(acc[nt][reg]);
    __syncthreads();

    if (y < 2) {
        unsigned short* out = (y == 0) ? Qw : Kw;
        int srow = l >> 2, hc = (l & 3) * 16;
        bf16x8 r0 = *(const bf16x8*)&et[w][srow][hc];
        bf16x8 r1 = *(const bf16x8*)&et[w][srow][hc + 8];
        unsigned short* op = out + (size_t)(row0 + srow) * H_ + hc;
        *(bf16x8*)op = r0;
        *(bf16x8*)(op + 8) = r1;
    } else {
        int h = l;
        bf16x8 t0, t1;
        #pragma unroll
        for (int r = 0; r < 8; ++r) t0[r] = et[w][r][h];
        #pragma unroll
        for (int r = 0; r < 8; ++r) t1[r] = et[w][r + 8][h];
        int b = row0 >> 12, sl = row0 & (S_ - 1);
        unsigned short* op = Vtw + ((size_t)b * H_ + h) * S_ + sl;
        *(bf16x8*)op = t0;
        *(bf16x8*)(op + 8) = t1;
    }
}

// ---------------------------------------------------------------------------
// Split-KV flash attention. grid (S/64, B, NSPLIT); 256 threads = 4 waves,
// 16 q-rows per wave; KV chunk of S/NSPLIT per block. Writes UNNORMALIZED
// partial O and (m, l) per q-row to workspace. LDS XOR-swizzled.
// ---------------------------------------------------------------------------
__global__ __launch_bounds__(256) void attn_kernel(
    const unsigned short* __restrict__ Qg, const unsigned short* __restrict__ Kg,
    const unsigned short* __restrict__ Vtg,
    float* __restrict__ Op, float2* __restrict__ Ml, int chunk)
{
    __shared__ __align__(16) unsigned short kt[64 * 64];
    __shared__ __align__(16) unsigned short vt[64 * 64];
    __shared__ __align__(16) unsigned short pt[4][16 * 64];

    const int tid = threadIdx.x;
    const int l = tid & 63, w = tid >> 6;
    const int lm = l & 15, lg = l >> 4;
    const int b = blockIdx.y;
    const int z = blockIdx.z;
    const int q0 = blockIdx.x * 64;
    const int kvbase = z * chunk;

    bf16x8 qa[2];
    {
        const unsigned short* qp = Qg + ((size_t)(b * S_ + q0 + w * 16 + lm)) * H_ + lg * 8;
        qa[0] = *(const bf16x8*)qp;
        qa[1] = *(const bf16x8*)(qp + 32);
    }

    f32x4 oa[4];
    float m[4], lsum[4];
    #pragma unroll
    for (int i = 0; i < 4; ++i) {
        oa[i] = (f32x4){0.f, 0.f, 0.f, 0.f};
        m[i] = -INFINITY;
        lsum[i] = 0.f;
    }
    unsigned short* ptw = pt[w];

    for (int kv0 = kvbase; kv0 < kvbase + chunk; kv0 += 64) {
        #pragma unroll
        for (int i = 0; i < 2; ++i) {
            int c = tid + 256 * i;
            int r = c >> 3, c8 = c & 7;
            bf16x8 kv8 = *(const bf16x8*)(Kg + ((size_t)(b * S_ + kv0 + r)) * H_ + c8 * 8);
            *(bf16x8*)((char*)kt + r * 128 + ((c8 * 16) ^ ((r & 7) << 4))) = kv8;
            bf16x8 vv8 = *(const bf16x8*)(Vtg + ((size_t)b * H_ + r) * S_ + kv0 + c8 * 8);
            *(bf16x8*)((char*)vt + r * 128 + ((c8 * 16) ^ ((r & 7) << 4))) = vv8;
        }
        __syncthreads();

        f32x4 s[4];
        #pragma unroll
        for (int nt = 0; nt < 4; ++nt) {
            f32x4 a = (f32x4){0.f, 0.f, 0.f, 0.f};
            int r = nt * 16 + lm;
            #pragma unroll
            for (int g2 = 0; g2 < 2; ++g2) {
                bf16x8 kb = *(const bf16x8*)((const char*)kt + r * 128 +
                                             ((lg * 16 + 64 * g2) ^ ((r & 7) << 4)));
                a = __builtin_amdgcn_mfma_f32_16x16x32_bf16(qa[g2], kb, a, 0, 0, 0);
            }
            s[nt] = a;
        }

        float p[4][4];
        #pragma unroll
        for (int reg = 0; reg < 4; ++reg) {
            float v = fmaxf(fmaxf(s[0][reg], s[1][reg]), fmaxf(s[2][reg], s[3][reg]));
            v = fmaxf(v, __shfl_xor(v, 1));
            v = fmaxf(v, __shfl_xor(v, 2));
            v = fmaxf(v, __shfl_xor(v, 4));
            v = fmaxf(v, __shfl_xor(v, 8));
            float mn = fmaxf(m[reg], v);
            float sc = __expf(m[reg] - mn);
            m[reg] = mn;
            float rs = 0.f;
            #pragma unroll
            for (int nt = 0; nt < 4; ++nt) {
                p[nt][reg] = __expf(s[nt][reg] - mn);
                rs += p[nt][reg];
            }
            rs += __shfl_xor(rs, 1);
            rs += __shfl_xor(rs, 2);
            rs += __shfl_xor(rs, 4);
            rs += __shfl_xor(rs, 8);
            lsum[reg] = lsum[reg] * sc + rs;
            #pragma unroll
            for (int nt = 0; nt < 4; ++nt) oa[nt][reg] *= sc;
        }

        #pragma unroll
        for (int nt = 0; nt < 4; ++nt)
            #pragma unroll
            for (int reg = 0; reg < 4; ++reg) {
                int row = lg * 4 + reg, col = nt * 16 + lm;
                *(unsigned short*)((char*)ptw + row * 128 + ((col * 2) ^ ((row & 7) << 4))) =
                    f2bf(p[nt][reg]);
            }
        __syncthreads();

        #pragma unroll
        for (int kk = 0; kk < 2; ++kk) {
            bf16x8 pa = *(const bf16x8*)((const char*)ptw + lm * 128 +
                                         ((lg * 16 + 64 * kk) ^ ((lm & 7) << 4)));
            #pragma unroll
            for (int nt = 0; nt < 4; ++nt) {
                int hr = nt * 16 + lm;
                bf16x8 vb = *(const bf16x8*)((const char*)vt + hr * 128 +
                                             ((lg * 16 + 64 * kk) ^ ((hr & 7) << 4)));
                oa[nt] = __builtin_amdgcn_mfma_f32_16x16x32_bf16(pa, vb, oa[nt], 0, 0, 0);
            }
        }
        __syncthreads();
    }

    const size_t zb = (size_t)z * B_ + b;
    #pragma unroll
    for (int nt = 0; nt < 4; ++nt)
        #pragma unroll
        for (int reg = 0; reg < 4; ++reg) {
            int q = q0 + w * 16 + lg * 4 + reg;
            int h = nt * 16 + lm;
            Op[(zb * S_ + q) * H_ + h] = oa[nt][reg];
        }
    if (lm == 0) {
        #pragma unroll
        for (int reg = 0; reg < 4; ++reg) {
            int q = q0 + w * 16 + lg * 4 + reg;
            Ml[zb * S_ + q] = make_float2(m[reg], lsum[reg]);
        }
    }
}

// ---------------------------------------------------------------------------
// Combine splits: out[b][q][h] = sum_i w_i*O_i / sum_i w_i*l_i.
// ---------------------------------------------------------------------------
__global__ __launch_bounds__(256) void combine_kernel(
    const float* __restrict__ Op, const float2* __restrict__ Ml,
    float* __restrict__ out, int nsplit)
{
    const int idx = blockIdx.x * 256 + threadIdx.x;
    const int bq = idx >> 4;
    const int h4 = (idx & 15) * 4;
    const size_t BS = (size_t)B_ * S_;

    float M = -INFINITY;
    for (int i = 0; i < nsplit; ++i) M = fmaxf(M, Ml[i * BS + bq].x);
    float L = 0.f;
    float4 acc = make_float4(0.f, 0.f, 0.f, 0.f);
    for (int i = 0; i < nsplit; ++i) {
        float2 ml = Ml[i * BS + bq];
        float wgt = __expf(ml.x - M);
        L += wgt * ml.y;
        float4 o = *(const float4*)(Op + (i * BS + bq) * H_ + h4);
        acc.x += wgt * o.x; acc.y += wgt * o.y; acc.z += wgt * o.z; acc.w += wgt * o.w;
    }
    float inv = 1.f / L;
    float4 r = make_float4(acc.x * inv, acc.y * inv, acc.z * inv, acc.w * inv);
    *(float4*)(out + (size_t)bq * H_ + h4) = r;
}

extern "C" void kernel_launch(void* const* d_in, const int* in_sizes, int n_in,
                              void* d_out, int out_size, void* d_ws, size_t ws_size,
                              hipStream_t stream) {
    const float* x  = (const float*)d_in[0];
    const float* Wq = (const float*)d_in[1];
    const float* Wk = (const float*)d_in[2];
    const float* Wv = (const float*)d_in[3];

    const size_t NQ = (size_t)B_ * S_ * H_;        // 1M elements
    unsigned short* Qw  = (unsigned short*)d_ws;   // 2 MB
    unsigned short* Kw  = Qw + NQ;                 // 2 MB
    unsigned short* Vtw = Kw + NQ;                 // 2 MB (transposed [b][h][s])
    unsigned short* WTw = Vtw + NQ;                // 384 KB (W^T concat bf16)
    char* p = (char*)(WTw + 192 * D_);

    const size_t per_split = NQ * 4 + (size_t)B_ * S_ * 8;
    size_t used = 3 * NQ * 2 + 192 * D_ * 2;
    int nsplit = 8;
    while (nsplit > 1 && used + (size_t)nsplit * per_split > ws_size) nsplit >>= 1;

    float*  Op = (float*)p;
    float2* Ml = (float2*)(p + (size_t)nsplit * NQ * 4);
    float* out = (float*)d_out;

    prep_w<<<192 * D_ / 256, 256, 0, stream>>>(Wq, Wk, Wv, WTw);

    dim3 pgrid(B_ * S_ / 64, 3);
    proj_mfma<<<pgrid, 256, 0, stream>>>(x, WTw, Qw, Kw, Vtw);

    dim3 agrid(S_ / 64, B_, nsplit);
    attn_kernel<<<agrid, 256, 0, stream>>>(Qw, Kw, Vtw, Op, Ml, S_ / nsplit);

    dim3 cgrid(B_ * S_ * 16 / 256);
    combine_kernel<<<cgrid, 256, 0, stream>>>(Op, Ml, out, nsplit);
}

// Round 5
// 92.124 us; speedup vs baseline: 1.5219x; 1.5219x over previous
//
#include <hip/hip_runtime.h>
#include <hip/hip_bf16.h>

#define B_ 4
#define S_ 4096
#define D_ 1024
#define H_ 64

typedef __attribute__((ext_vector_type(8))) short bf16x8;
typedef __attribute__((ext_vector_type(4))) float f32x4;

static __device__ __forceinline__ unsigned short f2bf(float f) {
    union { float f; unsigned int i; } v; v.f = f;
    unsigned int r = v.i + 0x7FFFu + ((v.i >> 16) & 1u);  // round-to-nearest-even
    return (unsigned short)(r >> 16);
}

typedef __attribute__((address_space(3))) unsigned int lds_u32;
typedef __attribute__((address_space(1))) const unsigned int glb_u32;
static __device__ __forceinline__ void gload16(const void* g, void* l) {
    __builtin_amdgcn_global_load_lds((glb_u32*)g, (lds_u32*)l, 16, 0, 0);
}

// ---------------------------------------------------------------------------
// prep_w: pack {Wq|Wk|Wv} (fp32 [1024][64]) into bf16 MFMA B-fragment order:
// WF[((nt*32 + g)*64 + lane)*8 + e] = W'[nt*16 + (lane&15)][g*32 + (lane>>4)*8 + e]
// where W' is the 192-col concat W^T (Q cols pre-scaled by 1/8).
// grid 12 blocks: bid -> (y = bid>>2, k-range (bid&3)*256). LDS-staged.
// ---------------------------------------------------------------------------
__global__ __launch_bounds__(256) void prep_w(
    const float* __restrict__ Wq, const float* __restrict__ Wk,
    const float* __restrict__ Wv, unsigned short* __restrict__ WF)
{
    __shared__ float wt[256][64];   // 64 KB
    const int bid = blockIdx.x;
    const int y = bid >> 2, kr = (bid & 3) * 256;
    const float* W = (y == 0) ? Wq : (y == 1) ? Wk : Wv;
    const float scale = (y == 0) ? 0.125f : 1.0f;
    const int t = threadIdx.x;

    #pragma unroll
    for (int it = 0; it < 16; ++it) {
        int idx = it * 256 + t;             // 4096 float4 slots
        int k = idx >> 4, h4 = (idx & 15) * 4;
        *(float4*)&wt[k][h4] = *(const float4*)(W + (size_t)(kr + k) * H_ + h4);
    }
    __syncthreads();

    const int ntl = t >> 6, l = t & 63, lm = l & 15, lg = l >> 4;
    const int h = ntl * 16 + lm;
    #pragma unroll
    for (int g = 0; g < 8; ++g) {
        bf16x8 v;
        #pragma unroll
        for (int e = 0; e < 8; ++e) v[e] = f2bf(wt[g * 32 + lg * 8 + e][h] * scale);
        int ntg = y * 4 + ntl, gg = (kr >> 5) + g;
        *(bf16x8*)(WF + ((size_t)(ntg * 32 + gg) * 64 + l) * 8) = v;
    }
}

// ---------------------------------------------------------------------------
// Fused QKV projection GEMM: [16384 x 1024] x [1024 x 192], bf16 MFMA.
// 512 threads = 8 waves (2M x 4N); wave = 32 rows x 48 cols; K-step 64.
// x staged fp32 -> LDS via global_load_lds (4-buffer ring, lookahead 2,
// counted vmcnt + raw s_barrier). Source addresses pre-XOR-swizzled so the
// linear LDS dest reads back conflict-free with swizzled ds_read_b128.
// B-frags from pre-packed WF (L2-resident), 1-step register prefetch.
// ---------------------------------------------------------------------------
__global__ __launch_bounds__(512) void proj_mfma(
    const float* __restrict__ x, const unsigned short* __restrict__ WF,
    unsigned short* __restrict__ Qw, unsigned short* __restrict__ Kw,
    unsigned short* __restrict__ Vtw)
{
    __shared__ __align__(16) char pool[65536];   // x ring: 4 x 16KB; reused as epilogue tile

    const int tid = threadIdx.x;
    const int w = tid >> 6, l = tid & 63;
    const int lm = l & 15, lg = l >> 4;
    const int wm = w >> 2, wn = w & 3;          // 2 M-groups x 4 N-groups
    const int row0 = blockIdx.x * 64;

    f32x4 acc[2][3];
    #pragma unroll
    for (int mt = 0; mt < 2; ++mt)
        #pragma unroll
        for (int n = 0; n < 3; ++n) acc[mt][n] = (f32x4){0.f, 0.f, 0.f, 0.f};

    // ---- stage x k64-step t into ring buffer (t&3); 2 gload_lds ops per wave
    auto stage = [&](int t) {
        #pragma unroll
        for (int j = 0; j < 2; ++j) {
            int i = (w * 2 + j) * 64 + l;                 // 16B slot index in 16KB tile
            int row = i >> 4;                             // 64 rows x 16 slots
            int u = ((i & 15) << 4) ^ ((row & 7) << 4);   // inverse-swizzled byte-in-row
            const char* g = (const char*)x + ((size_t)(row0 + row) << 12) + (t << 8) + u;
            char* dst = pool + (t & 3) * 16384 + ((w * 2 + j) << 10);  // wave-uniform
            gload16(g, dst);
        }
    };

    auto loadB = [&](int t, bf16x8* bf) {
        #pragma unroll
        for (int n = 0; n < 3; ++n)
            #pragma unroll
            for (int gg = 0; gg < 2; ++gg)
                bf[n * 2 + gg] = *(const bf16x8*)(WF +
                    ((size_t)((wn * 3 + n) * 32 + (t * 2 + gg)) * 64 + l) * 8);
    };

    auto compute = [&](int t, const bf16x8* bf) {
        const char* base = pool + (t & 3) * 16384;
        #pragma unroll
        for (int gg = 0; gg < 2; ++gg) {
            bf16x8 af[2];
            #pragma unroll
            for (int mt = 0; mt < 2; ++mt) {
                int r = wm * 32 + mt * 16 + lm;
                int sw = (r & 7) << 4;
                int c0 = gg * 128 + lg * 32;              // byte col in 256B row
                f32x4 a0 = *(const f32x4*)(base + r * 256 + (c0 ^ sw));
                f32x4 a1 = *(const f32x4*)(base + r * 256 + ((c0 + 16) ^ sw));
                af[mt][0] = f2bf(a0[0]); af[mt][1] = f2bf(a0[1]);
                af[mt][2] = f2bf(a0[2]); af[mt][3] = f2bf(a0[3]);
                af[mt][4] = f2bf(a1[0]); af[mt][5] = f2bf(a1[1]);
                af[mt][6] = f2bf(a1[2]); af[mt][7] = f2bf(a1[3]);
            }
            #pragma unroll
            for (int mt = 0; mt < 2; ++mt)
                #pragma unroll
                for (int n = 0; n < 3; ++n)
                    acc[mt][n] = __builtin_amdgcn_mfma_f32_16x16x32_bf16(
                        af[mt], bf[n * 2 + gg], acc[mt][n], 0, 0, 0);
        }
    };

    bf16x8 bA[6], bB[6];
    stage(0); stage(1); loadB(0, bA);

    #pragma unroll
    for (int tt = 0; tt < 16; tt += 2) {
        // ---- even step t = tt (uses bA, prefetches bB)
        if (tt + 2 < 16) stage(tt + 2);
        loadB(tt + 1, bB);
        if (tt < 14) { asm volatile("s_waitcnt vmcnt(8)" ::: "memory"); }
        else         { asm volatile("s_waitcnt vmcnt(6)" ::: "memory"); }
        __builtin_amdgcn_sched_barrier(0);
        __builtin_amdgcn_s_barrier();
        __builtin_amdgcn_sched_barrier(0);
        compute(tt, bA);

        // ---- odd step t = tt+1 (uses bB, prefetches bA)
        if (tt + 3 < 16) stage(tt + 3);
        if (tt + 2 < 16) loadB(tt + 2, bA);
        if (tt + 2 < 16) { asm volatile("s_waitcnt vmcnt(8)" ::: "memory"); }
        else             { asm volatile("s_waitcnt vmcnt(0)" ::: "memory"); }
        __builtin_amdgcn_sched_barrier(0);
        __builtin_amdgcn_s_barrier();
        __builtin_amdgcn_sched_barrier(0);
        compute(tt + 1, bB);
    }

    // ---- epilogue: acc -> LDS tile et[64][200] (reuses pool) -> coalesced global
    __syncthreads();
    unsigned short* et = (unsigned short*)pool;
    #pragma unroll
    for (int mt = 0; mt < 2; ++mt)
        #pragma unroll
        for (int n = 0; n < 3; ++n)
            #pragma unroll
            for (int reg = 0; reg < 4; ++reg)
                et[(wm * 32 + mt * 16 + lg * 4 + reg) * 200 + (wn * 48 + n * 16 + lm)] =
                    f2bf(acc[mt][n][reg]);
    __syncthreads();

    // Q,K: row-major bf16, 16B stores
    #pragma unroll
    for (int p = 0; p < 2; ++p) {
        int r = tid >> 3;
        int c = ((tid & 7) + p * 8) * 8;      // 0..127
        bf16x8 v = *(const bf16x8*)(et + r * 200 + c);
        unsigned short* dst = (c < 64) ? Qw : Kw;
        *(bf16x8*)(dst + (size_t)(row0 + r) * H_ + (c & 63)) = v;
    }
    // V: transposed Vt[b][h][s], 16B stores along s
    {
        int h = tid & 63, i0 = (tid >> 6) * 8;
        bf16x8 v;
        #pragma unroll
        for (int i = 0; i < 8; ++i) v[i] = et[(i0 + i) * 200 + 128 + h];
        int bat = row0 >> 12, s0 = (row0 & (S_ - 1)) + i0;
        *(bf16x8*)(Vtw + ((size_t)bat * H_ + h) * S_ + s0) = v;
    }
}

// ---------------------------------------------------------------------------
// Split-KV flash attention (unchanged, proven). grid (S/64, B, NSPLIT);
// 256 threads = 4 waves, 16 q-rows per wave; KV chunk of S/NSPLIT per block.
// Writes UNNORMALIZED partial O and (m, l) per q-row to workspace.
// ---------------------------------------------------------------------------
__global__ __launch_bounds__(256) void attn_kernel(
    const unsigned short* __restrict__ Qg, const unsigned short* __restrict__ Kg,
    const unsigned short* __restrict__ Vtg,
    float* __restrict__ Op, float2* __restrict__ Ml, int chunk)
{
    __shared__ __align__(16) unsigned short kt[64 * 64];
    __shared__ __align__(16) unsigned short vt[64 * 64];
    __shared__ __align__(16) unsigned short pt[4][16 * 64];

    const int tid = threadIdx.x;
    const int l = tid & 63, w = tid >> 6;
    const int lm = l & 15, lg = l >> 4;
    const int b = blockIdx.y;
    const int z = blockIdx.z;
    const int q0 = blockIdx.x * 64;
    const int kvbase = z * chunk;

    bf16x8 qa[2];
    {
        const unsigned short* qp = Qg + ((size_t)(b * S_ + q0 + w * 16 + lm)) * H_ + lg * 8;
        qa[0] = *(const bf16x8*)qp;
        qa[1] = *(const bf16x8*)(qp + 32);
    }

    f32x4 oa[4];
    float m[4], lsum[4];
    #pragma unroll
    for (int i = 0; i < 4; ++i) {
        oa[i] = (f32x4){0.f, 0.f, 0.f, 0.f};
        m[i] = -INFINITY;
        lsum[i] = 0.f;
    }
    unsigned short* ptw = pt[w];

    for (int kv0 = kvbase; kv0 < kvbase + chunk; kv0 += 64) {
        #pragma unroll
        for (int i = 0; i < 2; ++i) {
            int c = tid + 256 * i;
            int r = c >> 3, c8 = c & 7;
            bf16x8 kv8 = *(const bf16x8*)(Kg + ((size_t)(b * S_ + kv0 + r)) * H_ + c8 * 8);
            *(bf16x8*)((char*)kt + r * 128 + ((c8 * 16) ^ ((r & 7) << 4))) = kv8;
            bf16x8 vv8 = *(const bf16x8*)(Vtg + ((size_t)b * H_ + r) * S_ + kv0 + c8 * 8);
            *(bf16x8*)((char*)vt + r * 128 + ((c8 * 16) ^ ((r & 7) << 4))) = vv8;
        }
        __syncthreads();

        f32x4 s[4];
        #pragma unroll
        for (int nt = 0; nt < 4; ++nt) {
            f32x4 a = (f32x4){0.f, 0.f, 0.f, 0.f};
            int r = nt * 16 + lm;
            #pragma unroll
            for (int g2 = 0; g2 < 2; ++g2) {
                bf16x8 kb = *(const bf16x8*)((const char*)kt + r * 128 +
                                             ((lg * 16 + 64 * g2) ^ ((r & 7) << 4)));
                a = __builtin_amdgcn_mfma_f32_16x16x32_bf16(qa[g2], kb, a, 0, 0, 0);
            }
            s[nt] = a;
        }

        float p[4][4];
        #pragma unroll
        for (int reg = 0; reg < 4; ++reg) {
            float v = fmaxf(fmaxf(s[0][reg], s[1][reg]), fmaxf(s[2][reg], s[3][reg]));
            v = fmaxf(v, __shfl_xor(v, 1));
            v = fmaxf(v, __shfl_xor(v, 2));
            v = fmaxf(v, __shfl_xor(v, 4));
            v = fmaxf(v, __shfl_xor(v, 8));
            float mn = fmaxf(m[reg], v);
            float sc = __expf(m[reg] - mn);
            m[reg] = mn;
            float rs = 0.f;
            #pragma unroll
            for (int nt = 0; nt < 4; ++nt) {
                p[nt][reg] = __expf(s[nt][reg] - mn);
                rs += p[nt][reg];
            }
            rs += __shfl_xor(rs, 1);
            rs += __shfl_xor(rs, 2);
            rs += __shfl_xor(rs, 4);
            rs += __shfl_xor(rs, 8);
            lsum[reg] = lsum[reg] * sc + rs;
            #pragma unroll
            for (int nt = 0; nt < 4; ++nt) oa[nt][reg] *= sc;
        }

        #pragma unroll
        for (int nt = 0; nt < 4; ++nt)
            #pragma unroll
            for (int reg = 0; reg < 4; ++reg) {
                int row = lg * 4 + reg, col = nt * 16 + lm;
                *(unsigned short*)((char*)ptw + row * 128 + ((col * 2) ^ ((row & 7) << 4))) =
                    f2bf(p[nt][reg]);
            }
        __syncthreads();

        #pragma unroll
        for (int kk = 0; kk < 2; ++kk) {
            bf16x8 pa = *(const bf16x8*)((const char*)ptw + lm * 128 +
                                         ((lg * 16 + 64 * kk) ^ ((lm & 7) << 4)));
            #pragma unroll
            for (int nt = 0; nt < 4; ++nt) {
                int hr = nt * 16 + lm;
                bf16x8 vb = *(const bf16x8*)((const char*)vt + hr * 128 +
                                             ((lg * 16 + 64 * kk) ^ ((hr & 7) << 4)));
                oa[nt] = __builtin_amdgcn_mfma_f32_16x16x32_bf16(pa, vb, oa[nt], 0, 0, 0);
            }
        }
        __syncthreads();
    }

    const size_t zb = (size_t)z * B_ + b;
    #pragma unroll
    for (int nt = 0; nt < 4; ++nt)
        #pragma unroll
        for (int reg = 0; reg < 4; ++reg) {
            int q = q0 + w * 16 + lg * 4 + reg;
            int h = nt * 16 + lm;
            Op[(zb * S_ + q) * H_ + h] = oa[nt][reg];
        }
    if (lm == 0) {
        #pragma unroll
        for (int reg = 0; reg < 4; ++reg) {
            int q = q0 + w * 16 + lg * 4 + reg;
            Ml[zb * S_ + q] = make_float2(m[reg], lsum[reg]);
        }
    }
}

// ---------------------------------------------------------------------------
// Combine splits: out[b][q][h] = sum_i w_i*O_i / sum_i w_i*l_i.
// ---------------------------------------------------------------------------
__global__ __launch_bounds__(256) void combine_kernel(
    const float* __restrict__ Op, const float2* __restrict__ Ml,
    float* __restrict__ out, int nsplit)
{
    const int idx = blockIdx.x * 256 + threadIdx.x;
    const int bq = idx >> 4;
    const int h4 = (idx & 15) * 4;
    const size_t BS = (size_t)B_ * S_;

    float M = -INFINITY;
    for (int i = 0; i < nsplit; ++i) M = fmaxf(M, Ml[i * BS + bq].x);
    float L = 0.f;
    float4 acc = make_float4(0.f, 0.f, 0.f, 0.f);
    for (int i = 0; i < nsplit; ++i) {
        float2 ml = Ml[i * BS + bq];
        float wgt = __expf(ml.x - M);
        L += wgt * ml.y;
        float4 o = *(const float4*)(Op + (i * BS + bq) * H_ + h4);
        acc.x += wgt * o.x; acc.y += wgt * o.y; acc.z += wgt * o.z; acc.w += wgt * o.w;
    }
    float inv = 1.f / L;
    float4 r = make_float4(acc.x * inv, acc.y * inv, acc.z * inv, acc.w * inv);
    *(float4*)(out + (size_t)bq * H_ + h4) = r;
}

extern "C" void kernel_launch(void* const* d_in, const int* in_sizes, int n_in,
                              void* d_out, int out_size, void* d_ws, size_t ws_size,
                              hipStream_t stream) {
    const float* x  = (const float*)d_in[0];
    const float* Wq = (const float*)d_in[1];
    const float* Wk = (const float*)d_in[2];
    const float* Wv = (const float*)d_in[3];

    const size_t NQ = (size_t)B_ * S_ * H_;        // 1M elements
    unsigned short* Qw  = (unsigned short*)d_ws;   // 2 MB
    unsigned short* Kw  = Qw + NQ;                 // 2 MB
    unsigned short* Vtw = Kw + NQ;                 // 2 MB (transposed [b][h][s])
    unsigned short* WFw = Vtw + NQ;                // 384 KB (fragment-packed W)
    char* p = (char*)(WFw + 192 * D_);

    const size_t per_split = NQ * 4 + (size_t)B_ * S_ * 8;
    size_t used = 3 * NQ * 2 + 192 * D_ * 2;
    int nsplit = 8;
    while (nsplit > 1 && used + (size_t)nsplit * per_split > ws_size) nsplit >>= 1;

    float*  Op = (float*)p;
    float2* Ml = (float2*)(p + (size_t)nsplit * NQ * 4);
    float* out = (float*)d_out;

    prep_w<<<12, 256, 0, stream>>>(Wq, Wk, Wv, WFw);

    proj_mfma<<<B_ * S_ / 64, 512, 0, stream>>>(x, WFw, Qw, Kw, Vtw);

    dim3 agrid(S_ / 64, B_, nsplit);
    attn_kernel<<<agrid, 256, 0, stream>>>(Qw, Kw, Vtw, Op, Ml, S_ / nsplit);

    dim3 cgrid(B_ * S_ * 16 / 256);
    combine_kernel<<<cgrid, 256, 0, stream>>>(Op, Ml, out, nsplit);
}

// Round 6
// 74.859 us; speedup vs baseline: 1.8729x; 1.2306x over previous
//
#include <hip/hip_runtime.h>
#include <hip/hip_bf16.h>

#define B_ 4
#define S_ 4096
#define D_ 1024
#define H_ 64

typedef __attribute__((ext_vector_type(8))) short bf16x8;
typedef __attribute__((ext_vector_type(4))) float f32x4;

static __device__ __forceinline__ unsigned short f2bf(float f) {
    union { float f; unsigned int i; } v; v.f = f;
    unsigned int r = v.i + 0x7FFFu + ((v.i >> 16) & 1u);  // round-to-nearest-even
    return (unsigned short)(r >> 16);
}

typedef __attribute__((address_space(3))) unsigned int lds_u32;
typedef __attribute__((address_space(1))) const unsigned int glb_u32;
static __device__ __forceinline__ void gload16(const void* g, void* l) {
    __builtin_amdgcn_global_load_lds((glb_u32*)g, (lds_u32*)l, 16, 0, 0);
}

// ---------------------------------------------------------------------------
// prep_w: pack {Wq|Wk|Wv} (fp32 [1024][64]) into bf16 MFMA B-fragment order.
// Q columns pre-scaled by log2(e)/8 (base-2 softmax domain).
// ---------------------------------------------------------------------------
__global__ __launch_bounds__(256) void prep_w(
    const float* __restrict__ Wq, const float* __restrict__ Wk,
    const float* __restrict__ Wv, unsigned short* __restrict__ WF)
{
    __shared__ float wt[256][64];   // 64 KB
    const int bid = blockIdx.x;
    const int y = bid >> 2, kr = (bid & 3) * 256;
    const float* W = (y == 0) ? Wq : (y == 1) ? Wk : Wv;
    const float scale = (y == 0) ? 0.125f * 1.4426950408889634f : 1.0f;
    const int t = threadIdx.x;

    #pragma unroll
    for (int it = 0; it < 16; ++it) {
        int idx = it * 256 + t;
        int k = idx >> 4, h4 = (idx & 15) * 4;
        *(float4*)&wt[k][h4] = *(const float4*)(W + (size_t)(kr + k) * H_ + h4);
    }
    __syncthreads();

    const int ntl = t >> 6, l = t & 63, lm = l & 15, lg = l >> 4;
    const int h = ntl * 16 + lm;
    #pragma unroll
    for (int g = 0; g < 8; ++g) {
        bf16x8 v;
        #pragma unroll
        for (int e = 0; e < 8; ++e) v[e] = f2bf(wt[g * 32 + lg * 8 + e][h] * scale);
        int ntg = y * 4 + ntl, gg = (kr >> 5) + g;
        *(bf16x8*)(WF + ((size_t)(ntg * 32 + gg) * 64 + l) * 8) = v;
    }
}

// ---------------------------------------------------------------------------
// Fused QKV projection GEMM (unchanged from round 4, proven ~15us):
// [16384 x 1024] x [1024 x 192] bf16 MFMA; x staged via global_load_lds ring.
// ---------------------------------------------------------------------------
__global__ __launch_bounds__(512) void proj_mfma(
    const float* __restrict__ x, const unsigned short* __restrict__ WF,
    unsigned short* __restrict__ Qw, unsigned short* __restrict__ Kw,
    unsigned short* __restrict__ Vtw)
{
    __shared__ __align__(16) char pool[65536];

    const int tid = threadIdx.x;
    const int w = tid >> 6, l = tid & 63;
    const int lm = l & 15, lg = l >> 4;
    const int wm = w >> 2, wn = w & 3;
    const int row0 = blockIdx.x * 64;

    f32x4 acc[2][3];
    #pragma unroll
    for (int mt = 0; mt < 2; ++mt)
        #pragma unroll
        for (int n = 0; n < 3; ++n) acc[mt][n] = (f32x4){0.f, 0.f, 0.f, 0.f};

    auto stage = [&](int t) {
        #pragma unroll
        for (int j = 0; j < 2; ++j) {
            int i = (w * 2 + j) * 64 + l;
            int row = i >> 4;
            int u = ((i & 15) << 4) ^ ((row & 7) << 4);
            const char* g = (const char*)x + ((size_t)(row0 + row) << 12) + (t << 8) + u;
            char* dst = pool + (t & 3) * 16384 + ((w * 2 + j) << 10);
            gload16(g, dst);
        }
    };

    auto loadB = [&](int t, bf16x8* bf) {
        #pragma unroll
        for (int n = 0; n < 3; ++n)
            #pragma unroll
            for (int gg = 0; gg < 2; ++gg)
                bf[n * 2 + gg] = *(const bf16x8*)(WF +
                    ((size_t)((wn * 3 + n) * 32 + (t * 2 + gg)) * 64 + l) * 8);
    };

    auto compute = [&](int t, const bf16x8* bf) {
        const char* base = pool + (t & 3) * 16384;
        #pragma unroll
        for (int gg = 0; gg < 2; ++gg) {
            bf16x8 af[2];
            #pragma unroll
            for (int mt = 0; mt < 2; ++mt) {
                int r = wm * 32 + mt * 16 + lm;
                int sw = (r & 7) << 4;
                int c0 = gg * 128 + lg * 32;
                f32x4 a0 = *(const f32x4*)(base + r * 256 + (c0 ^ sw));
                f32x4 a1 = *(const f32x4*)(base + r * 256 + ((c0 + 16) ^ sw));
                af[mt][0] = f2bf(a0[0]); af[mt][1] = f2bf(a0[1]);
                af[mt][2] = f2bf(a0[2]); af[mt][3] = f2bf(a0[3]);
                af[mt][4] = f2bf(a1[0]); af[mt][5] = f2bf(a1[1]);
                af[mt][6] = f2bf(a1[2]); af[mt][7] = f2bf(a1[3]);
            }
            #pragma unroll
            for (int mt = 0; mt < 2; ++mt)
                #pragma unroll
                for (int n = 0; n < 3; ++n)
                    acc[mt][n] = __builtin_amdgcn_mfma_f32_16x16x32_bf16(
                        af[mt], bf[n * 2 + gg], acc[mt][n], 0, 0, 0);
        }
    };

    bf16x8 bA[6], bB[6];
    stage(0); stage(1); loadB(0, bA);

    #pragma unroll
    for (int tt = 0; tt < 16; tt += 2) {
        if (tt + 2 < 16) stage(tt + 2);
        loadB(tt + 1, bB);
        if (tt < 14) { asm volatile("s_waitcnt vmcnt(8)" ::: "memory"); }
        else         { asm volatile("s_waitcnt vmcnt(6)" ::: "memory"); }
        __builtin_amdgcn_sched_barrier(0);
        __builtin_amdgcn_s_barrier();
        __builtin_amdgcn_sched_barrier(0);
        compute(tt, bA);

        if (tt + 3 < 16) stage(tt + 3);
        if (tt + 2 < 16) loadB(tt + 2, bA);
        if (tt + 2 < 16) { asm volatile("s_waitcnt vmcnt(8)" ::: "memory"); }
        else             { asm volatile("s_waitcnt vmcnt(0)" ::: "memory"); }
        __builtin_amdgcn_sched_barrier(0);
        __builtin_amdgcn_s_barrier();
        __builtin_amdgcn_sched_barrier(0);
        compute(tt + 1, bB);
    }

    __syncthreads();
    unsigned short* et = (unsigned short*)pool;
    #pragma unroll
    for (int mt = 0; mt < 2; ++mt)
        #pragma unroll
        for (int n = 0; n < 3; ++n)
            #pragma unroll
            for (int reg = 0; reg < 4; ++reg)
                et[(wm * 32 + mt * 16 + lg * 4 + reg) * 200 + (wn * 48 + n * 16 + lm)] =
                    f2bf(acc[mt][n][reg]);
    __syncthreads();

    #pragma unroll
    for (int p = 0; p < 2; ++p) {
        int r = tid >> 3;
        int c = ((tid & 7) + p * 8) * 8;
        bf16x8 v = *(const bf16x8*)(et + r * 200 + c);
        unsigned short* dst = (c < 64) ? Qw : Kw;
        *(bf16x8*)(dst + (size_t)(row0 + r) * H_ + (c & 63)) = v;
    }
    {
        int h = tid & 63, i0 = (tid >> 6) * 8;
        bf16x8 v;
        #pragma unroll
        for (int i = 0; i < 8; ++i) v[i] = et[(i0 + i) * 200 + 128 + h];
        int bat = row0 >> 12, s0 = (row0 & (S_ - 1)) + i0;
        *(bf16x8*)(Vtw + ((size_t)bat * H_ + h) * S_ + s0) = v;
    }
}

// ---------------------------------------------------------------------------
// Split-KV flash attention, swapped-QK^T structure.
// grid (S/64, B, NSPLIT); 256 threads = 4 waves, 16 q-rows/wave (q = lane&15).
// S^T = mfma(K, Q): each lane owns one q-row -> softmax reduce = 15 in-reg ops
// + 2 shuffles. Base-2 domain (Q pre-scaled by log2e/8). P packed with
// v_cvt_pk_bf16_f32 into per-wave LDS (no barrier). O^T = mfma(V^T, P).
// K/V double-buffered via global_load_lds; ONE barrier per KV tile.
// ---------------------------------------------------------------------------
__global__ __launch_bounds__(256) void attn_kernel(
    const unsigned short* __restrict__ Qg, const unsigned short* __restrict__ Kg,
    const unsigned short* __restrict__ Vtg,
    float* __restrict__ Op, float2* __restrict__ Ml, int chunk)
{
    __shared__ __align__(16) char kv_lds[2][16384];        // [buf]: K 8KB | V 8KB
    __shared__ __align__(16) unsigned short pt[4][1024];   // per-wave P [q=16][kv=64]

    const int tid = threadIdx.x;
    const int l = tid & 63, w = tid >> 6;
    const int lm = l & 15, lg = l >> 4;
    const int b = blockIdx.y, z = blockIdx.z;
    const int q0 = blockIdx.x * 64;
    const int kvbase = z * chunk;
    const int ntile = chunk >> 6;

    // Q fragment (B-operand of swapped QK^T): qa[g2][e] = Q[q=lm row][g2*32+lg*8+e]
    bf16x8 qa[2];
    {
        const unsigned short* qp = Qg + ((size_t)(b * S_ + q0 + w * 16 + lm)) * H_ + lg * 8;
        qa[0] = *(const bf16x8*)qp;
        qa[1] = *(const bf16x8*)(qp + 32);
    }

    f32x4 oa[4];                                    // O^T frags: h = nt*16+lg*4+reg, q = lm
    #pragma unroll
    for (int nt = 0; nt < 4; ++nt) oa[nt] = (f32x4){0.f, 0.f, 0.f, 0.f};
    float m = -INFINITY, lsum = 0.f;
    unsigned short* ptw = pt[w];

    const char* Kb = (const char*)Kg + ((size_t)b * S_ + kvbase) * (H_ * 2);
    const char* Vb = (const char*)Vtg + ((size_t)b * H_) * (S_ * 2) + (size_t)kvbase * 2;

    // stage KV tile t into buf: 16 x 1KB gload_lds (4/wave), source pre-swizzled
    auto stage = [&](int t, int buf) {
        #pragma unroll
        for (int j = 0; j < 2; ++j) {
            int slot = w * 2 + j;                       // 0..7
            int row = slot * 8 + (l >> 3), c16 = l & 7;
            int u = (c16 * 16) ^ ((row & 7) << 4);
            gload16(Kb + (size_t)(t * 64 + row) * 128 + u,
                    &kv_lds[buf][slot * 1024]);
            gload16(Vb + (size_t)row * (S_ * 2) + t * 128 + u,
                    &kv_lds[buf][8192 + slot * 1024]);
        }
    };

    stage(0, 0);
    asm volatile("s_waitcnt vmcnt(0)" ::: "memory");
    __builtin_amdgcn_s_barrier();

    for (int t = 0; t < ntile; ++t) {
        const int cur = t & 1;
        if (t + 1 < ntile) stage(t + 1, cur ^ 1);

        const char* kbase = kv_lds[cur];
        const char* vbase = kv_lds[cur] + 8192;

        // ---- S^T = K Q^T : rows = kv (nt*16 + lg*4 + reg), col = q = lm
        f32x4 sv[4];
        #pragma unroll
        for (int nt = 0; nt < 4; ++nt) {
            f32x4 a = (f32x4){0.f, 0.f, 0.f, 0.f};
            int r = nt * 16 + lm, sw = (r & 7) << 4;
            #pragma unroll
            for (int g2 = 0; g2 < 2; ++g2) {
                bf16x8 kb = *(const bf16x8*)(kbase + r * 128 + ((g2 * 64 + lg * 16) ^ sw));
                a = __builtin_amdgcn_mfma_f32_16x16x32_bf16(kb, qa[g2], a, 0, 0, 0);
            }
            sv[nt] = a;
        }

        // ---- online softmax, base-2, one q-row per lane
        float tmax = sv[0][0];
        #pragma unroll
        for (int nt = 0; nt < 4; ++nt)
            #pragma unroll
            for (int reg = 0; reg < 4; ++reg) tmax = fmaxf(tmax, sv[nt][reg]);
        tmax = fmaxf(tmax, __shfl_xor(tmax, 16));
        tmax = fmaxf(tmax, __shfl_xor(tmax, 32));
        float mn = fmaxf(m, tmax);
        float sc = exp2f(m - mn);
        m = mn;
        float p[4][4];
        float rs = 0.f;
        #pragma unroll
        for (int nt = 0; nt < 4; ++nt)
            #pragma unroll
            for (int reg = 0; reg < 4; ++reg) {
                p[nt][reg] = exp2f(sv[nt][reg] - mn);
                rs += p[nt][reg];
            }
        rs += __shfl_xor(rs, 16);
        rs += __shfl_xor(rs, 32);
        lsum = lsum * sc + rs;
        #pragma unroll
        for (int nt = 0; nt < 4; ++nt) {
            oa[nt][0] *= sc; oa[nt][1] *= sc; oa[nt][2] *= sc; oa[nt][3] *= sc;
        }

        // ---- pack P to bf16 pairs, write per-wave LDS row q=lm (no barrier)
        #pragma unroll
        for (int nt = 0; nt < 4; ++nt)
            #pragma unroll
            for (int j = 0; j < 2; ++j) {
                unsigned int w32;
                asm("v_cvt_pk_bf16_f32 %0, %1, %2"
                    : "=v"(w32) : "v"(p[nt][2 * j]), "v"(p[nt][2 * j + 1]));
                *(unsigned int*)((char*)ptw + lm * 128 +
                                 ((nt * 32 + lg * 8 + j * 4) ^ ((lm & 7) << 4))) = w32;
            }
        asm volatile("s_waitcnt lgkmcnt(0)" ::: "memory");
        __builtin_amdgcn_sched_barrier(0);

        // ---- O^T += V^T P : A = V^T rows (h), B = P rows (q = lm)
        #pragma unroll
        for (int kk = 0; kk < 2; ++kk) {
            bf16x8 pb = *(const bf16x8*)((const char*)ptw + lm * 128 +
                                         ((kk * 64 + lg * 16) ^ ((lm & 7) << 4)));
            #pragma unroll
            for (int nt = 0; nt < 4; ++nt) {
                int hr = nt * 16 + lm;
                bf16x8 vb = *(const bf16x8*)(vbase + hr * 128 +
                                             ((kk * 64 + lg * 16) ^ ((hr & 7) << 4)));
                oa[nt] = __builtin_amdgcn_mfma_f32_16x16x32_bf16(vb, pb, oa[nt], 0, 0, 0);
            }
        }

        asm volatile("s_waitcnt vmcnt(0)" ::: "memory");
        __builtin_amdgcn_sched_barrier(0);
        __builtin_amdgcn_s_barrier();
        __builtin_amdgcn_sched_barrier(0);
    }

    // ---- write unnormalized partials (per lane: q = lm, h = nt*16+lg*4+reg)
    const size_t zb = (size_t)z * B_ + b;
    const size_t qrow = zb * S_ + q0 + w * 16 + lm;
    #pragma unroll
    for (int nt = 0; nt < 4; ++nt)
        *(f32x4*)(Op + qrow * H_ + nt * 16 + lg * 4) = oa[nt];
    if (lg == 0) Ml[qrow] = make_float2(m, lsum);
}

// ---------------------------------------------------------------------------
// Combine splits (base-2 weights): out = sum_i 2^(m_i-M) O_i / sum_i 2^(m_i-M) l_i
// ---------------------------------------------------------------------------
__global__ __launch_bounds__(256) void combine_kernel(
    const float* __restrict__ Op, const float2* __restrict__ Ml,
    float* __restrict__ out, int nsplit)
{
    const int idx = blockIdx.x * 256 + threadIdx.x;
    const int bq = idx >> 4;
    const int h4 = (idx & 15) * 4;
    const size_t BS = (size_t)B_ * S_;

    float M = -INFINITY;
    for (int i = 0; i < nsplit; ++i) M = fmaxf(M, Ml[i * BS + bq].x);
    float L = 0.f;
    float4 acc = make_float4(0.f, 0.f, 0.f, 0.f);
    for (int i = 0; i < nsplit; ++i) {
        float2 ml = Ml[i * BS + bq];
        float wgt = exp2f(ml.x - M);
        L += wgt * ml.y;
        float4 o = *(const float4*)(Op + (i * BS + bq) * H_ + h4);
        acc.x += wgt * o.x; acc.y += wgt * o.y; acc.z += wgt * o.z; acc.w += wgt * o.w;
    }
    float inv = 1.f / L;
    float4 r = make_float4(acc.x * inv, acc.y * inv, acc.z * inv, acc.w * inv);
    *(float4*)(out + (size_t)bq * H_ + h4) = r;
}

extern "C" void kernel_launch(void* const* d_in, const int* in_sizes, int n_in,
                              void* d_out, int out_size, void* d_ws, size_t ws_size,
                              hipStream_t stream) {
    const float* x  = (const float*)d_in[0];
    const float* Wq = (const float*)d_in[1];
    const float* Wk = (const float*)d_in[2];
    const float* Wv = (const float*)d_in[3];

    const size_t NQ = (size_t)B_ * S_ * H_;        // 1M elements
    unsigned short* Qw  = (unsigned short*)d_ws;   // 2 MB
    unsigned short* Kw  = Qw + NQ;                 // 2 MB
    unsigned short* Vtw = Kw + NQ;                 // 2 MB (transposed [b][h][s])
    unsigned short* WFw = Vtw + NQ;                // 384 KB (fragment-packed W)
    char* p = (char*)(WFw + 192 * D_);

    const size_t per_split = NQ * 4 + (size_t)B_ * S_ * 8;
    size_t used = 3 * NQ * 2 + 192 * D_ * 2;
    int nsplit = 4;
    while (nsplit > 1 && used + (size_t)nsplit * per_split > ws_size) nsplit >>= 1;

    float*  Op = (float*)p;
    float2* Ml = (float2*)(p + (size_t)nsplit * NQ * 4);
    float* out = (float*)d_out;

    prep_w<<<12, 256, 0, stream>>>(Wq, Wk, Wv, WFw);

    proj_mfma<<<B_ * S_ / 64, 512, 0, stream>>>(x, WFw, Qw, Kw, Vtw);

    dim3 agrid(S_ / 64, B_, nsplit);
    attn_kernel<<<agrid, 256, 0, stream>>>(Qw, Kw, Vtw, Op, Ml, S_ / nsplit);

    dim3 cgrid(B_ * S_ * 16 / 256);
    combine_kernel<<<cgrid, 256, 0, stream>>>(Op, Ml, out, nsplit);
}